// Round 3
// baseline (523.792 us; speedup 1.0000x reference)
//
#include <hip/hip_runtime.h>

#define TN 64
#define NB 2
#define CH 8
#define HH 128
#define WW 128
#define HW (HH*WW)        // 16384
#define CHW (CH*HW)       // 131072
#define NCHW (NB*CHW)     // 262144

// ---------------------------------------------------------------------------
// K1: psp1 alpha filter (tau=1). One thread per (n,c,h,w) element.
// ---------------------------------------------------------------------------
__global__ __launch_bounds__(256) void k_psp1(const float* __restrict__ x,
                                              float* __restrict__ psp1) {
    int e = blockIdx.x * blockDim.x + threadIdx.x;
    if (e >= NCHW) return;
    const float d1 = 0.36787944117144233f;  // exp(-1)
    const float c1 = 2.7182818284590452f;   // e * Ts/tau * Ts
    float P = 0.f, Q = 0.f;
    const float4* xe = reinterpret_cast<const float4*>(x + (size_t)e * TN);
    #pragma unroll
    for (int t4 = 0; t4 < TN / 4; ++t4) {
        float4 xv = xe[t4];
        float xs[4] = {xv.x, xv.y, xv.z, xv.w};
        #pragma unroll
        for (int j = 0; j < 4; ++j) {
            Q = d1 * (Q + P);
            P = d1 * P + xs[j];
            psp1[(size_t)(t4 * 4 + j) * NCHW + e] = c1 * Q;
        }
    }
}

// ---------------------------------------------------------------------------
// K2: conv1 5x5 pad=2, 8->8 ch. Block = 256 thr -> 32x32 output tile.
// Each thread: 1x4 output strip, all 8 co (acc[8][4]).
// LDS: only 2 input channels staged at a time -> [2][36][40] = 11.5 KB.
// Per (ci,dy): 3 aligned ds_read_b128 feed 160 FMAs.
// ---------------------------------------------------------------------------
__global__ __launch_bounds__(256) void k_conv1(const float* __restrict__ in,
                                               const float* __restrict__ w1,
                                               float* __restrict__ outp) {
    __shared__ __align__(16) float tile[2][36][40];
    const int img = blockIdx.y;                       // t*NB + n, 0..127
    const int h0 = (blockIdx.x >> 2) * 32;
    const int w0 = (blockIdx.x & 3) * 32;
    const int ty = threadIdx.x >> 3;                  // 0..31 output row
    const int x0 = (threadIdx.x & 7) * 4;             // 0..28 strip start
    const float* base = in + (size_t)img * CHW;

    // channel-agnostic staging slots: 36x36 = 1296 elements per channel
    int ldsoff[6], goff[6];
    #pragma unroll
    for (int k = 0; k < 6; ++k) {
        int idx = threadIdx.x + (k << 8);
        if (idx < 1296) {
            int r = idx / 36, col = idx - r * 36;
            int gh = h0 + r - 2, gw = w0 + col - 2;
            ldsoff[k] = r * 40 + col;
            goff[k] = (gh >= 0 && gh < HH && gw >= 0 && gw < WW) ? gh * WW + gw : -1;
        } else {
            ldsoff[k] = -1; goff[k] = -1;
        }
    }

    float acc[CH][4];
    #pragma unroll
    for (int co = 0; co < CH; ++co)
        #pragma unroll
        for (int p = 0; p < 4; ++p) acc[co][p] = 0.f;

    float* lds = &tile[0][0][0];
    #pragma unroll
    for (int cig = 0; cig < 4; ++cig) {
        const int ci0 = cig * 2;
        #pragma unroll
        for (int k = 0; k < 6; ++k) {
            if (ldsoff[k] >= 0) {
                float v0 = (goff[k] >= 0) ? base[ci0 * HW + goff[k]] : 0.f;
                float v1 = (goff[k] >= 0) ? base[(ci0 + 1) * HW + goff[k]] : 0.f;
                lds[ldsoff[k]] = v0;
                lds[1440 + ldsoff[k]] = v1;
            }
        }
        __syncthreads();

        #pragma unroll
        for (int c = 0; c < 2; ++c) {
            const int ci = ci0 + c;
            #pragma unroll
            for (int dy = 0; dy < 5; ++dy) {
                const float4* rp = reinterpret_cast<const float4*>(&tile[c][ty + dy][x0]);
                float4 r0 = rp[0], r1 = rp[1], r2 = rp[2];
                float win[12] = {r0.x, r0.y, r0.z, r0.w,
                                 r1.x, r1.y, r1.z, r1.w,
                                 r2.x, r2.y, r2.z, r2.w};
                #pragma unroll
                for (int co = 0; co < CH; ++co) {
                    #pragma unroll
                    for (int kx = 0; kx < 5; ++kx) {
                        float wv = w1[(co * CH + ci) * 25 + dy * 5 + kx];
                        acc[co][0] = fmaf(wv, win[kx],     acc[co][0]);
                        acc[co][1] = fmaf(wv, win[kx + 1], acc[co][1]);
                        acc[co][2] = fmaf(wv, win[kx + 2], acc[co][2]);
                        acc[co][3] = fmaf(wv, win[kx + 3], acc[co][3]);
                    }
                }
            }
        }
        __syncthreads();
    }

    float* ob = outp + (size_t)img * CHW + (h0 + ty) * WW + (w0 + x0);
    #pragma unroll
    for (int co = 0; co < CH; ++co)
        *reinterpret_cast<float4*>(ob + co * HW) =
            make_float4(acc[co][0], acc[co][1], acc[co][2], acc[co][3]);
}

// ---------------------------------------------------------------------------
// K3: LIF1 (theta=30, tauRef=1) + psp2 alpha filter (tau=2), fused pointwise.
// ---------------------------------------------------------------------------
__global__ __launch_bounds__(256) void k_lif1_psp2(const float* __restrict__ u1,
                                                   float* __restrict__ psp2) {
    int e = blockIdx.x * blockDim.x + threadIdx.x;
    if (e >= NCHW) return;
    const float dr = 0.36787944117144233f;  // exp(-1)
    const float rg = 81.54845485377136f;    // 30*e
    const float th = 30.f;
    const float d2 = 0.60653065971263342f;  // exp(-0.5)
    const float c2 = 1.35914091422952262f;  // e/2
    float Pr = 0.f, Qr = 0.f, P2 = 0.f, Q2 = 0.f;
    #pragma unroll 8
    for (int t = 0; t < TN; ++t) {
        Qr = dr * (Qr + Pr);
        float u = u1[(size_t)t * NCHW + e];
        float s = (u - rg * Qr >= th) ? 1.0f : 0.0f;
        Pr = dr * Pr + s;
        Q2 = d2 * (Q2 + P2);
        P2 = d2 * P2 + s;
        psp2[(size_t)t * NCHW + e] = c2 * Q2;
    }
}

// ---------------------------------------------------------------------------
// K4: conv2 3x3 pad=1, 8->8 ch. Same structure as K2.
// LDS [2][34][36] = 9.8 KB; per (ci,dy): 2 ds_read_b128 feed 96 FMAs.
// ---------------------------------------------------------------------------
__global__ __launch_bounds__(256) void k_conv2(const float* __restrict__ in,
                                               const float* __restrict__ w2,
                                               float* __restrict__ outp) {
    __shared__ __align__(16) float tile[2][34][36];
    const int img = blockIdx.y;
    const int h0 = (blockIdx.x >> 2) * 32;
    const int w0 = (blockIdx.x & 3) * 32;
    const int ty = threadIdx.x >> 3;
    const int x0 = (threadIdx.x & 7) * 4;
    const float* base = in + (size_t)img * CHW;

    // 34x34 = 1156 elements per channel
    int ldsoff[5], goff[5];
    #pragma unroll
    for (int k = 0; k < 5; ++k) {
        int idx = threadIdx.x + (k << 8);
        if (idx < 1156) {
            int r = idx / 34, col = idx - r * 34;
            int gh = h0 + r - 1, gw = w0 + col - 1;
            ldsoff[k] = r * 36 + col;
            goff[k] = (gh >= 0 && gh < HH && gw >= 0 && gw < WW) ? gh * WW + gw : -1;
        } else {
            ldsoff[k] = -1; goff[k] = -1;
        }
    }

    float acc[CH][4];
    #pragma unroll
    for (int co = 0; co < CH; ++co)
        #pragma unroll
        for (int p = 0; p < 4; ++p) acc[co][p] = 0.f;

    float* lds = &tile[0][0][0];
    #pragma unroll
    for (int cig = 0; cig < 4; ++cig) {
        const int ci0 = cig * 2;
        #pragma unroll
        for (int k = 0; k < 5; ++k) {
            if (ldsoff[k] >= 0) {
                float v0 = (goff[k] >= 0) ? base[ci0 * HW + goff[k]] : 0.f;
                float v1 = (goff[k] >= 0) ? base[(ci0 + 1) * HW + goff[k]] : 0.f;
                lds[ldsoff[k]] = v0;
                lds[1224 + ldsoff[k]] = v1;
            }
        }
        __syncthreads();

        #pragma unroll
        for (int c = 0; c < 2; ++c) {
            const int ci = ci0 + c;
            #pragma unroll
            for (int dy = 0; dy < 3; ++dy) {
                const float4* rp = reinterpret_cast<const float4*>(&tile[c][ty + dy][x0]);
                float4 r0 = rp[0], r1 = rp[1];
                float win[8] = {r0.x, r0.y, r0.z, r0.w, r1.x, r1.y, r1.z, r1.w};
                #pragma unroll
                for (int co = 0; co < CH; ++co) {
                    #pragma unroll
                    for (int kx = 0; kx < 3; ++kx) {
                        float wv = w2[(co * CH + ci) * 9 + dy * 3 + kx];
                        acc[co][0] = fmaf(wv, win[kx],     acc[co][0]);
                        acc[co][1] = fmaf(wv, win[kx + 1], acc[co][1]);
                        acc[co][2] = fmaf(wv, win[kx + 2], acc[co][2]);
                        acc[co][3] = fmaf(wv, win[kx + 3], acc[co][3]);
                    }
                }
            }
        }
        __syncthreads();
    }

    float* ob = outp + (size_t)img * CHW + (h0 + ty) * WW + (w0 + x0);
    #pragma unroll
    for (int co = 0; co < CH; ++co)
        *reinterpret_cast<float4*>(ob + co * HW) =
            make_float4(acc[co][0], acc[co][1], acc[co][2], acc[co][3]);
}

// ---------------------------------------------------------------------------
// K5: LIF2 (theta=50, tauRef=2). Buffers 64 spikes in registers, writes
// output [N,C,H,W,T] (t-contiguous per thread) as float4.
// ---------------------------------------------------------------------------
__global__ __launch_bounds__(256) void k_lif2(const float* __restrict__ u2,
                                              float* __restrict__ outp) {
    int e = blockIdx.x * blockDim.x + threadIdx.x;
    if (e >= NCHW) return;
    const float dr = 0.60653065971263342f;  // exp(-0.5)
    const float rg = 67.95704571147613f;    // 25*e
    const float th = 50.f;
    float Pr = 0.f, Qr = 0.f;
    float sv[TN];
    #pragma unroll
    for (int t = 0; t < TN; ++t) {
        Qr = dr * (Qr + Pr);
        float u = u2[(size_t)t * NCHW + e];
        float s = (u - rg * Qr >= th) ? 1.0f : 0.0f;
        Pr = dr * Pr + s;
        sv[t] = s;
    }
    float4* o = reinterpret_cast<float4*>(outp + (size_t)e * TN);
    #pragma unroll
    for (int i = 0; i < TN / 4; ++i)
        o[i] = make_float4(sv[4 * i], sv[4 * i + 1], sv[4 * i + 2], sv[4 * i + 3]);
}

// ---------------------------------------------------------------------------
extern "C" void kernel_launch(void* const* d_in, const int* in_sizes, int n_in,
                              void* d_out, int out_size, void* d_ws, size_t ws_size,
                              hipStream_t stream) {
    const float* x  = (const float*)d_in[0];   // [2,8,128,128,64]
    const float* w1 = (const float*)d_in[1];   // [8,8,5,5]
    const float* w2 = (const float*)d_in[2];   // [8,8,3,3]
    float* out = (float*)d_out;                // [2,8,128,128,64]

    float* bufA = (float*)d_ws;                       // psp1, then psp2
    float* bufB = bufA + (size_t)TN * NCHW;           // u1,   then u2

    dim3 blk(256);
    dim3 grd_pt(NCHW / 256);          // 1024 blocks, pointwise kernels
    dim3 grd_cv(16, TN * NB);         // 16 tiles (32x32) x 128 images

    k_psp1<<<grd_pt, blk, 0, stream>>>(x, bufA);
    k_conv1<<<grd_cv, blk, 0, stream>>>(bufA, w1, bufB);
    k_lif1_psp2<<<grd_pt, blk, 0, stream>>>(bufB, bufA);
    k_conv2<<<grd_cv, blk, 0, stream>>>(bufA, w2, bufB);
    k_lif2<<<grd_pt, blk, 0, stream>>>(bufB, out);
}

// Round 4
// 216.087 us; speedup vs baseline: 2.4240x; 2.4240x over previous
//
#include <hip/hip_runtime.h>

#define TN 64
#define NB 2
#define CH 8
#define HH 128
#define WW 128
#define HW (HH*WW)        // 16384
#define CHW (CH*HW)       // 131072
#define NCHW (NB*CHW)     // 262144

// ---------------------------------------------------------------------------
// K1: psp1 alpha filter (tau=1). One thread per (n,c,h,w) element.
// ---------------------------------------------------------------------------
__global__ __launch_bounds__(256) void k_psp1(const float* __restrict__ x,
                                              float* __restrict__ psp1) {
    int e = blockIdx.x * blockDim.x + threadIdx.x;
    if (e >= NCHW) return;
    const float d1 = 0.36787944117144233f;  // exp(-1)
    const float c1 = 2.7182818284590452f;   // e * Ts/tau * Ts
    float P = 0.f, Q = 0.f;
    const float4* xe = reinterpret_cast<const float4*>(x + (size_t)e * TN);
    #pragma unroll
    for (int t4 = 0; t4 < TN / 4; ++t4) {
        float4 xv = xe[t4];
        float xs[4] = {xv.x, xv.y, xv.z, xv.w};
        #pragma unroll
        for (int j = 0; j < 4; ++j) {
            Q = d1 * (Q + P);
            P = d1 * P + xs[j];
            psp1[(size_t)(t4 * 4 + j) * NCHW + e] = c1 * Q;
        }
    }
}

// ---------------------------------------------------------------------------
// K2: conv1 5x5 pad=2, 8->8 ch. Block = 256 thr = 8 full-width rows.
// Lane strip: 4 consecutive x (x0 = 4*(tid&31)); row = tid>>5.
// LDS [2ch][12 rows][136] (13 KB), halo shift +2 makes all float4 reads
// 16B-aligned; half-wave lanes read one row consecutively -> conflict-free.
// Per (ci,ky): 2 ds_read_b128 feed 160 FMAs. acc[8][4] = 32 VGPR.
// ---------------------------------------------------------------------------
__global__ __launch_bounds__(256, 4) void k_conv1(const float* __restrict__ in,
                                                  const float* __restrict__ w1,
                                                  float* __restrict__ outp) {
    __shared__ __align__(16) float tile[2][12][136];
    const int img = blockIdx.y;                 // t*NB + n, 0..127
    const int h0 = blockIdx.x * 8;              // 16 y-tiles
    const int tid = threadIdx.x;
    const int lx = tid & 31;
    const int yi = tid >> 5;                    // 0..7
    const int x0 = lx * 4;                      // 0..124
    const float* base = in + (size_t)img * CHW;
    float* lds = &tile[0][0][0];

    float acc[CH][4];
    #pragma unroll
    for (int co = 0; co < CH; ++co)
        #pragma unroll
        for (int xo = 0; xo < 4; ++xo) acc[co][xo] = 0.f;

    for (int cig = 0; cig < 4; ++cig) {
        const int ci0 = cig * 2;
        if (cig) __syncthreads();
        for (int slot = tid; slot < 1632; slot += 256) {   // 12*136
            int r = slot / 136;
            int c = slot - r * 136;
            int gh = h0 + r - 2, gw = c - 2;
            bool ok = (gh >= 0 && gh < HH && gw >= 0 && gw < WW);
            int g = gh * WW + gw;
            lds[slot]        = ok ? base[ci0 * HW + g]       : 0.f;
            lds[1632 + slot] = ok ? base[(ci0 + 1) * HW + g] : 0.f;
        }
        __syncthreads();

        #pragma unroll
        for (int c = 0; c < 2; ++c) {
            const int ci = ci0 + c;
            const float* chp = lds + c * 1632;
            #pragma unroll
            for (int ky = 0; ky < 5; ++ky) {
                const float4* rp =
                    reinterpret_cast<const float4*>(chp + (yi + ky) * 136 + x0);
                float4 a = rp[0], b = rp[1];
                float f[8] = {a.x, a.y, a.z, a.w, b.x, b.y, b.z, b.w};
                #pragma unroll
                for (int co = 0; co < CH; ++co) {
                    const float* wp = w1 + (co * CH + ci) * 25 + ky * 5;
                    #pragma unroll
                    for (int kx = 0; kx < 5; ++kx) {
                        float wv = wp[kx];
                        #pragma unroll
                        for (int xo = 0; xo < 4; ++xo)
                            acc[co][xo] = fmaf(wv, f[kx + xo], acc[co][xo]);
                    }
                }
            }
        }
    }

    float* ob = outp + (size_t)img * CHW + (h0 + yi) * WW + x0;
    #pragma unroll
    for (int co = 0; co < CH; ++co)
        *reinterpret_cast<float4*>(ob + co * HW) =
            make_float4(acc[co][0], acc[co][1], acc[co][2], acc[co][3]);
}

// ---------------------------------------------------------------------------
// K3: LIF1 (theta=30, tauRef=1) + psp2 alpha filter (tau=2), fused pointwise.
// ---------------------------------------------------------------------------
__global__ __launch_bounds__(256) void k_lif1_psp2(const float* __restrict__ u1,
                                                   float* __restrict__ psp2) {
    int e = blockIdx.x * blockDim.x + threadIdx.x;
    if (e >= NCHW) return;
    const float dr = 0.36787944117144233f;  // exp(-1)
    const float rg = 81.54845485377136f;    // 30*e
    const float th = 30.f;
    const float d2 = 0.60653065971263342f;  // exp(-0.5)
    const float c2 = 1.35914091422952262f;  // e/2
    float Pr = 0.f, Qr = 0.f, P2 = 0.f, Q2 = 0.f;
    #pragma unroll 8
    for (int t = 0; t < TN; ++t) {
        Qr = dr * (Qr + Pr);
        float u = u1[(size_t)t * NCHW + e];
        float s = (u - rg * Qr >= th) ? 1.0f : 0.0f;
        Pr = dr * Pr + s;
        Q2 = d2 * (Q2 + P2);
        P2 = d2 * P2 + s;
        psp2[(size_t)t * NCHW + e] = c2 * Q2;
    }
}

// ---------------------------------------------------------------------------
// K4: conv2 3x3 pad=1, 8->8 ch. Same structure as K2.
// LDS [2][10][136] = 10.9 KB; per (ci,ky): 2 ds_read_b128 feed 96 FMAs.
// ---------------------------------------------------------------------------
__global__ __launch_bounds__(256, 4) void k_conv2(const float* __restrict__ in,
                                                  const float* __restrict__ w2,
                                                  float* __restrict__ outp) {
    __shared__ __align__(16) float tile[2][10][136];
    const int img = blockIdx.y;
    const int h0 = blockIdx.x * 8;
    const int tid = threadIdx.x;
    const int lx = tid & 31;
    const int yi = tid >> 5;
    const int x0 = lx * 4;
    const float* base = in + (size_t)img * CHW;
    float* lds = &tile[0][0][0];

    float acc[CH][4];
    #pragma unroll
    for (int co = 0; co < CH; ++co)
        #pragma unroll
        for (int xo = 0; xo < 4; ++xo) acc[co][xo] = 0.f;

    for (int cig = 0; cig < 4; ++cig) {
        const int ci0 = cig * 2;
        if (cig) __syncthreads();
        for (int slot = tid; slot < 1360; slot += 256) {   // 10*136
            int r = slot / 136;
            int c = slot - r * 136;
            int gh = h0 + r - 1, gw = c - 1;
            bool ok = (gh >= 0 && gh < HH && gw >= 0 && gw < WW);
            int g = gh * WW + gw;
            lds[slot]        = ok ? base[ci0 * HW + g]       : 0.f;
            lds[1360 + slot] = ok ? base[(ci0 + 1) * HW + g] : 0.f;
        }
        __syncthreads();

        #pragma unroll
        for (int c = 0; c < 2; ++c) {
            const int ci = ci0 + c;
            const float* chp = lds + c * 1360;
            #pragma unroll
            for (int ky = 0; ky < 3; ++ky) {
                const float4* rp =
                    reinterpret_cast<const float4*>(chp + (yi + ky) * 136 + x0);
                float4 a = rp[0], b = rp[1];
                float f[8] = {a.x, a.y, a.z, a.w, b.x, b.y, b.z, b.w};
                #pragma unroll
                for (int co = 0; co < CH; ++co) {
                    const float* wp = w2 + (co * CH + ci) * 9 + ky * 3;
                    #pragma unroll
                    for (int kx = 0; kx < 3; ++kx) {
                        float wv = wp[kx];
                        #pragma unroll
                        for (int xo = 0; xo < 4; ++xo)
                            acc[co][xo] = fmaf(wv, f[kx + xo], acc[co][xo]);
                    }
                }
            }
        }
    }

    float* ob = outp + (size_t)img * CHW + (h0 + yi) * WW + x0;
    #pragma unroll
    for (int co = 0; co < CH; ++co)
        *reinterpret_cast<float4*>(ob + co * HW) =
            make_float4(acc[co][0], acc[co][1], acc[co][2], acc[co][3]);
}

// ---------------------------------------------------------------------------
// K5: LIF2 (theta=50, tauRef=2). Buffers 64 spikes in registers, writes
// output [N,C,H,W,T] (t-contiguous per thread) as float4.
// ---------------------------------------------------------------------------
__global__ __launch_bounds__(256) void k_lif2(const float* __restrict__ u2,
                                              float* __restrict__ outp) {
    int e = blockIdx.x * blockDim.x + threadIdx.x;
    if (e >= NCHW) return;
    const float dr = 0.60653065971263342f;  // exp(-0.5)
    const float rg = 67.95704571147613f;    // 25*e
    const float th = 50.f;
    float Pr = 0.f, Qr = 0.f;
    float sv[TN];
    #pragma unroll
    for (int t = 0; t < TN; ++t) {
        Qr = dr * (Qr + Pr);
        float u = u2[(size_t)t * NCHW + e];
        float s = (u - rg * Qr >= th) ? 1.0f : 0.0f;
        Pr = dr * Pr + s;
        sv[t] = s;
    }
    float4* o = reinterpret_cast<float4*>(outp + (size_t)e * TN);
    #pragma unroll
    for (int i = 0; i < TN / 4; ++i)
        o[i] = make_float4(sv[4 * i], sv[4 * i + 1], sv[4 * i + 2], sv[4 * i + 3]);
}

// ---------------------------------------------------------------------------
extern "C" void kernel_launch(void* const* d_in, const int* in_sizes, int n_in,
                              void* d_out, int out_size, void* d_ws, size_t ws_size,
                              hipStream_t stream) {
    const float* x  = (const float*)d_in[0];   // [2,8,128,128,64]
    const float* w1 = (const float*)d_in[1];   // [8,8,5,5]
    const float* w2 = (const float*)d_in[2];   // [8,8,3,3]
    float* out = (float*)d_out;                // [2,8,128,128,64]

    float* bufA = (float*)d_ws;                       // psp1, then psp2
    float* bufB = bufA + (size_t)TN * NCHW;           // u1,   then u2

    dim3 blk(256);
    dim3 grd_pt(NCHW / 256);          // 1024 blocks, pointwise kernels
    dim3 grd_cv(16, TN * NB);         // 16 row-tiles (8 rows) x 128 images

    k_psp1<<<grd_pt, blk, 0, stream>>>(x, bufA);
    k_conv1<<<grd_cv, blk, 0, stream>>>(bufA, w1, bufB);
    k_lif1_psp2<<<grd_pt, blk, 0, stream>>>(bufB, bufA);
    k_conv2<<<grd_cv, blk, 0, stream>>>(bufA, w2, bufB);
    k_lif2<<<grd_pt, blk, 0, stream>>>(bufB, out);
}

// Round 5
// 204.662 us; speedup vs baseline: 2.5593x; 1.0558x over previous
//
#include <hip/hip_runtime.h>

#define TN 64
#define NB 2
#define CH 8
#define HH 128
#define WW 128
#define HW (HH*WW)        // 16384
#define CHW (CH*HW)       // 131072
#define NCHW (NB*CHW)     // 262144

// ---------------------------------------------------------------------------
// K1: psp1 alpha filter (tau=1). One thread per (n,c,h,w) element.
// ---------------------------------------------------------------------------
__global__ __launch_bounds__(256) void k_psp1(const float* __restrict__ x,
                                              float* __restrict__ psp1) {
    int e = blockIdx.x * blockDim.x + threadIdx.x;
    if (e >= NCHW) return;
    const float d1 = 0.36787944117144233f;  // exp(-1)
    const float c1 = 2.7182818284590452f;   // e * Ts/tau * Ts
    float P = 0.f, Q = 0.f;
    const float4* xe = reinterpret_cast<const float4*>(x + (size_t)e * TN);
    #pragma unroll
    for (int t4 = 0; t4 < TN / 4; ++t4) {
        float4 xv = xe[t4];
        float xs[4] = {xv.x, xv.y, xv.z, xv.w};
        #pragma unroll
        for (int j = 0; j < 4; ++j) {
            Q = d1 * (Q + P);
            P = d1 * P + xs[j];
            psp1[(size_t)(t4 * 4 + j) * NCHW + e] = c1 * Q;
        }
    }
}

// ---------------------------------------------------------------------------
// K2: conv1 5x5 pad=2. Block = 256 thr = 8 full-width rows; lane strip 4x.
// Double-buffered LDS [2buf][2ch][12][136] = 26.1 KB, 1 barrier/phase.
// goff[] hoisted (computed once); prefetch next channel-pair into regs
// during compute (T14 async-stage). Per (ci,ky): 2 ds_read_b128 -> 160 FMA.
// ---------------------------------------------------------------------------
__global__ __launch_bounds__(256, 4) void k_conv1(const float* __restrict__ in,
                                                  const float* __restrict__ w1,
                                                  float* __restrict__ outp) {
    __shared__ __align__(16) float tile[2][2][12][136];
    const int img = blockIdx.y;                 // t*NB + n, 0..127
    const int h0 = blockIdx.x * 8;              // 16 y-tiles
    const int tid = threadIdx.x;
    const int yi = tid >> 5;                    // 0..7
    const int x0 = (tid & 31) * 4;              // 0..124
    const float* base = in + (size_t)img * CHW;

    // staging offsets: computed ONCE, reused for all 4 channel-pair phases
    int goff[7];
    #pragma unroll
    for (int k = 0; k < 7; ++k) {
        int idx = tid + (k << 8);
        int r = idx / 136;
        int c = idx - r * 136;
        int gh = h0 + r - 2, gw = c - 2;
        bool ok = (idx < 1632) && (gh >= 0) && (gh < HH) && (gw >= 0) && (gw < WW);
        goff[k] = ok ? (gh * WW + gw) : -1;
    }

    float va[7], vb[7];
    // prefetch channel pair 0 (branchless clamped loads)
    #pragma unroll
    for (int k = 0; k < 7; ++k) {
        int g = goff[k];
        int gc = g < 0 ? 0 : g;
        float t0 = base[gc], t1 = base[HW + gc];
        va[k] = g < 0 ? 0.f : t0;
        vb[k] = g < 0 ? 0.f : t1;
    }

    float acc[CH][4];
    #pragma unroll
    for (int co = 0; co < CH; ++co)
        #pragma unroll
        for (int xo = 0; xo < 4; ++xo) acc[co][xo] = 0.f;

    for (int cig = 0; cig < 4; ++cig) {
        float* dst = &tile[cig & 1][0][0][0];
        #pragma unroll
        for (int k = 0; k < 7; ++k) {
            int idx = tid + (k << 8);
            if (k < 6 || idx < 1632) {
                dst[idx]        = va[k];
                dst[1632 + idx] = vb[k];
            }
        }
        if (cig < 3) {                           // prefetch next pair -> regs
            const float* nb = base + (size_t)(cig + 1) * 2 * HW;
            #pragma unroll
            for (int k = 0; k < 7; ++k) {
                int g = goff[k];
                int gc = g < 0 ? 0 : g;
                float t0 = nb[gc], t1 = nb[HW + gc];
                va[k] = g < 0 ? 0.f : t0;
                vb[k] = g < 0 ? 0.f : t1;
            }
        }
        __syncthreads();                         // staged data visible

        const float* bufp = &tile[cig & 1][0][0][0];
        #pragma unroll
        for (int c = 0; c < 2; ++c) {
            const int ci = cig * 2 + c;
            const float* chp = bufp + c * 1632;
            #pragma unroll
            for (int ky = 0; ky < 5; ++ky) {
                const float4* rp =
                    reinterpret_cast<const float4*>(chp + (yi + ky) * 136 + x0);
                float4 A = rp[0], B = rp[1];
                float f[8] = {A.x, A.y, A.z, A.w, B.x, B.y, B.z, B.w};
                #pragma unroll
                for (int co = 0; co < CH; ++co) {
                    const float* wp = w1 + (co * CH + ci) * 25 + ky * 5;
                    #pragma unroll
                    for (int kx = 0; kx < 5; ++kx) {
                        float wv = wp[kx];
                        #pragma unroll
                        for (int xo = 0; xo < 4; ++xo)
                            acc[co][xo] = fmaf(wv, f[kx + xo], acc[co][xo]);
                    }
                }
            }
        }
        // no trailing barrier: next phase writes the OTHER LDS buffer
    }

    float* ob = outp + (size_t)img * CHW + (h0 + yi) * WW + x0;
    #pragma unroll
    for (int co = 0; co < CH; ++co)
        *reinterpret_cast<float4*>(ob + co * HW) =
            make_float4(acc[co][0], acc[co][1], acc[co][2], acc[co][3]);
}

// ---------------------------------------------------------------------------
// K3: LIF1 (theta=30, tauRef=1) + psp2 alpha filter (tau=2), fused pointwise.
// ---------------------------------------------------------------------------
__global__ __launch_bounds__(256) void k_lif1_psp2(const float* __restrict__ u1,
                                                   float* __restrict__ psp2) {
    int e = blockIdx.x * blockDim.x + threadIdx.x;
    if (e >= NCHW) return;
    const float dr = 0.36787944117144233f;  // exp(-1)
    const float rg = 81.54845485377136f;    // 30*e
    const float th = 30.f;
    const float d2 = 0.60653065971263342f;  // exp(-0.5)
    const float c2 = 1.35914091422952262f;  // e/2
    float Pr = 0.f, Qr = 0.f, P2 = 0.f, Q2 = 0.f;
    #pragma unroll 8
    for (int t = 0; t < TN; ++t) {
        Qr = dr * (Qr + Pr);
        float u = u1[(size_t)t * NCHW + e];
        float s = (u - rg * Qr >= th) ? 1.0f : 0.0f;
        Pr = dr * Pr + s;
        Q2 = d2 * (Q2 + P2);
        P2 = d2 * P2 + s;
        psp2[(size_t)t * NCHW + e] = c2 * Q2;
    }
}

// ---------------------------------------------------------------------------
// K4: conv2 3x3 pad=1. Same structure as K2.
// LDS [2][2][10][136] = 21.8 KB; per (ci,ky): 2 ds_read_b128 -> 96 FMA.
// ---------------------------------------------------------------------------
__global__ __launch_bounds__(256, 4) void k_conv2(const float* __restrict__ in,
                                                  const float* __restrict__ w2,
                                                  float* __restrict__ outp) {
    __shared__ __align__(16) float tile[2][2][10][136];
    const int img = blockIdx.y;
    const int h0 = blockIdx.x * 8;
    const int tid = threadIdx.x;
    const int yi = tid >> 5;
    const int x0 = (tid & 31) * 4;
    const float* base = in + (size_t)img * CHW;

    int goff[6];
    #pragma unroll
    for (int k = 0; k < 6; ++k) {
        int idx = tid + (k << 8);
        int r = idx / 136;
        int c = idx - r * 136;
        int gh = h0 + r - 1, gw = c - 1;
        bool ok = (idx < 1360) && (gh >= 0) && (gh < HH) && (gw >= 0) && (gw < WW);
        goff[k] = ok ? (gh * WW + gw) : -1;
    }

    float va[6], vb[6];
    #pragma unroll
    for (int k = 0; k < 6; ++k) {
        int g = goff[k];
        int gc = g < 0 ? 0 : g;
        float t0 = base[gc], t1 = base[HW + gc];
        va[k] = g < 0 ? 0.f : t0;
        vb[k] = g < 0 ? 0.f : t1;
    }

    float acc[CH][4];
    #pragma unroll
    for (int co = 0; co < CH; ++co)
        #pragma unroll
        for (int xo = 0; xo < 4; ++xo) acc[co][xo] = 0.f;

    for (int cig = 0; cig < 4; ++cig) {
        float* dst = &tile[cig & 1][0][0][0];
        #pragma unroll
        for (int k = 0; k < 6; ++k) {
            int idx = tid + (k << 8);
            if (k < 5 || idx < 1360) {
                dst[idx]        = va[k];
                dst[1360 + idx] = vb[k];
            }
        }
        if (cig < 3) {
            const float* nb = base + (size_t)(cig + 1) * 2 * HW;
            #pragma unroll
            for (int k = 0; k < 6; ++k) {
                int g = goff[k];
                int gc = g < 0 ? 0 : g;
                float t0 = nb[gc], t1 = nb[HW + gc];
                va[k] = g < 0 ? 0.f : t0;
                vb[k] = g < 0 ? 0.f : t1;
            }
        }
        __syncthreads();

        const float* bufp = &tile[cig & 1][0][0][0];
        #pragma unroll
        for (int c = 0; c < 2; ++c) {
            const int ci = cig * 2 + c;
            const float* chp = bufp + c * 1360;
            #pragma unroll
            for (int ky = 0; ky < 3; ++ky) {
                const float4* rp =
                    reinterpret_cast<const float4*>(chp + (yi + ky) * 136 + x0);
                float4 A = rp[0], B = rp[1];
                float f[8] = {A.x, A.y, A.z, A.w, B.x, B.y, B.z, B.w};
                #pragma unroll
                for (int co = 0; co < CH; ++co) {
                    const float* wp = w2 + (co * CH + ci) * 9 + ky * 3;
                    #pragma unroll
                    for (int kx = 0; kx < 3; ++kx) {
                        float wv = wp[kx];
                        #pragma unroll
                        for (int xo = 0; xo < 4; ++xo)
                            acc[co][xo] = fmaf(wv, f[kx + xo], acc[co][xo]);
                    }
                }
            }
        }
    }

    float* ob = outp + (size_t)img * CHW + (h0 + yi) * WW + x0;
    #pragma unroll
    for (int co = 0; co < CH; ++co)
        *reinterpret_cast<float4*>(ob + co * HW) =
            make_float4(acc[co][0], acc[co][1], acc[co][2], acc[co][3]);
}

// ---------------------------------------------------------------------------
// K5: LIF2 (theta=50, tauRef=2). Buffers 64 spikes in registers, writes
// output [N,C,H,W,T] (t-contiguous per thread) as float4.
// ---------------------------------------------------------------------------
__global__ __launch_bounds__(256) void k_lif2(const float* __restrict__ u2,
                                              float* __restrict__ outp) {
    int e = blockIdx.x * blockDim.x + threadIdx.x;
    if (e >= NCHW) return;
    const float dr = 0.60653065971263342f;  // exp(-0.5)
    const float rg = 67.95704571147613f;    // 25*e
    const float th = 50.f;
    float Pr = 0.f, Qr = 0.f;
    float sv[TN];
    #pragma unroll
    for (int t = 0; t < TN; ++t) {
        Qr = dr * (Qr + Pr);
        float u = u2[(size_t)t * NCHW + e];
        float s = (u - rg * Qr >= th) ? 1.0f : 0.0f;
        Pr = dr * Pr + s;
        sv[t] = s;
    }
    float4* o = reinterpret_cast<float4*>(outp + (size_t)e * TN);
    #pragma unroll
    for (int i = 0; i < TN / 4; ++i)
        o[i] = make_float4(sv[4 * i], sv[4 * i + 1], sv[4 * i + 2], sv[4 * i + 3]);
}

// ---------------------------------------------------------------------------
extern "C" void kernel_launch(void* const* d_in, const int* in_sizes, int n_in,
                              void* d_out, int out_size, void* d_ws, size_t ws_size,
                              hipStream_t stream) {
    const float* x  = (const float*)d_in[0];   // [2,8,128,128,64]
    const float* w1 = (const float*)d_in[1];   // [8,8,5,5]
    const float* w2 = (const float*)d_in[2];   // [8,8,3,3]
    float* out = (float*)d_out;                // [2,8,128,128,64]

    float* bufA = (float*)d_ws;                       // psp1, then psp2
    float* bufB = bufA + (size_t)TN * NCHW;           // u1,   then u2

    dim3 blk(256);
    dim3 grd_pt(NCHW / 256);          // 1024 blocks, pointwise kernels
    dim3 grd_cv(16, TN * NB);         // 16 row-tiles (8 rows) x 128 images

    k_psp1<<<grd_pt, blk, 0, stream>>>(x, bufA);
    k_conv1<<<grd_cv, blk, 0, stream>>>(bufA, w1, bufB);
    k_lif1_psp2<<<grd_pt, blk, 0, stream>>>(bufB, bufA);
    k_conv2<<<grd_cv, blk, 0, stream>>>(bufA, w2, bufB);
    k_lif2<<<grd_pt, blk, 0, stream>>>(bufB, out);
}